// Round 17
// baseline (243.213 us; speedup 1.0000x reference)
//
#include <hip/hip_runtime.h>
#include <cstdint>
#include <cstddef>

#define D_MODEL 2048
#define SEQ 2048
#define BATCH 2
#define HEADS 16
#define DH 128
#define MROWS (BATCH * SEQ) /* 4096 */

typedef __attribute__((ext_vector_type(8))) short short8;
typedef __attribute__((ext_vector_type(4))) float f32x4;
typedef __attribute__((ext_vector_type(16))) float f32x16;
typedef __attribute__((ext_vector_type(2))) unsigned int uint2e;

__device__ __forceinline__ unsigned short f2bf(float f) {
    unsigned int u = __builtin_bit_cast(unsigned int, f);
    u += 0x7fffu + ((u >> 16) & 1u);   // round-to-nearest-even
    return (unsigned short)(u >> 16);
}

__device__ __forceinline__ unsigned int cvt_pk_bf16(float lo, float hi) {
    unsigned int w;
    asm("v_cvt_pk_bf16_f32 %0, %1, %2" : "=v"(w) : "v"(lo), "v"(hi));
    return w;
}

__device__ __forceinline__ void swap32(unsigned int& x, unsigned int& y) {
#if __has_builtin(__builtin_amdgcn_permlane32_swap)
    uint2e r = __builtin_amdgcn_permlane32_swap(x, y, false, false);
    x = r[0]; y = r[1];
#else
    const int hi = (threadIdx.x >> 5) & 1;
    const unsigned int gx = (unsigned int)__shfl_xor((int)x, 32);
    const unsigned int gy = (unsigned int)__shfl_xor((int)y, 32);
    const unsigned int nx = hi ? gy : x;
    const unsigned int ny = hi ? y : gx;
    x = nx; y = ny;
#endif
}

__device__ __forceinline__ void gload_lds16(const unsigned short* g, unsigned short* l) {
    __builtin_amdgcn_global_load_lds(
        (const __attribute__((address_space(1))) void*)g,
        (__attribute__((address_space(3))) void*)l, 16, 0, 0);
}

// ---------------- fused fp32 -> bf16 conversion (x + 4 weights, one launch) ------
__global__ __launch_bounds__(256) void cvt_all(const float* __restrict__ x,
                                               const float* __restrict__ wq,
                                               const float* __restrict__ wk,
                                               const float* __restrict__ wv,
                                               const float* __restrict__ wo,
                                               unsigned short* __restrict__ out) {
    constexpr int PX = (MROWS * D_MODEL) / 4;
    constexpr int PW = (D_MODEL * D_MODEL) / 4;
    int i = blockIdx.x * 256 + threadIdx.x;
    const float* s;
    int off;
    if (i < PX) { s = x; off = i; }
    else {
        const int j = i - PX;
        const int sel = j / PW;
        off = j - sel * PW;
        s = sel == 0 ? wq : sel == 1 ? wk : sel == 2 ? wv : wo;
    }
    const float4 v = reinterpret_cast<const float4*>(s)[off];
    ushort4 o;
    o.x = f2bf(v.x); o.y = f2bf(v.y); o.z = f2bf(v.z); o.w = f2bf(v.w);
    reinterpret_cast<ushort4*>(out)[i] = o;
}

// ============ 8-phase 256x256 GEMM for Q+K — SPREAD-LOAD schedule ============
__global__ __launch_bounds__(512, 2)
void gemm8qk(const unsigned short* __restrict__ A,
             const unsigned short* __restrict__ W0,
             const unsigned short* __restrict__ W1,
             const float* __restrict__ b0f,
             const float* __restrict__ b1f,
             unsigned short* __restrict__ O0,
             unsigned short* __restrict__ O1) {
    constexpr int BK = 64;
    constexpr int K = D_MODEL;
    constexpr int NT_N = 16;
    constexpr int NWG = 16 * NT_N;           // 256
    __shared__ unsigned short As[2][16384];
    __shared__ unsigned short Bs[2][16384];

    const int tid  = threadIdx.x;
    const int lane = tid & 63;
    const int wid  = tid >> 6;

    const int wk = (blockIdx.x & 7) * (NWG >> 3) + (blockIdx.x >> 3);
    const int nt = wk % NT_N;
    const int mt = wk / NT_N;
    const int m0 = mt * 256;
    const int nsel = nt >> 3;
    const int nloc = (nt & 7) * 256;

    const unsigned short* Bw = nsel ? W1 : W0;
    const float* bias = nsel ? b1f : b0f;

    const int srow = tid >> 3;
    const int sch  = tid & 7;
    const int ssw  = (sch ^ (srow & 7)) * 8;
    const int sd   = srow * 64 + sch * 8;
    const unsigned short* aS[4];
    const unsigned short* bS[4];
#pragma unroll
    for (int j = 0; j < 4; ++j) {
        aS[j] = A  + (size_t)(m0 + j * 64 + srow) * K + ssw;
        bS[j] = Bw + (size_t)(nloc + j * 64 + srow) * K + ssw;
    }

    const int fr = lane & 15, fg = lane >> 4;
    const int wm = wid >> 2, wn = wid & 3;
    int aoffs[2], boffs[2];
#pragma unroll
    for (int ks = 0; ks < 2; ++ks) {
        const int sw = ((ks * 4 + fg) ^ (fr & 7)) * 8;
        aoffs[ks] = (wm * 128 + fr) * 64 + sw;
        boffs[ks] = (wn * 64 + fr) * 64 + sw;
    }

    f32x4 acc[8][4] = {};

#define STG2_A01(SET, T)                                             \
    gload_lds16(aS[0] + (T) * BK, &As[SET][0 * 4096 + sd]);          \
    gload_lds16(aS[1] + (T) * BK, &As[SET][1 * 4096 + sd]);
#define STG2_A23(SET, T)                                             \
    gload_lds16(aS[2] + (T) * BK, &As[SET][2 * 4096 + sd]);          \
    gload_lds16(aS[3] + (T) * BK, &As[SET][3 * 4096 + sd]);
#define STG2_B01(SET, T)                                             \
    gload_lds16(bS[0] + (T) * BK, &Bs[SET][0 * 4096 + sd]);          \
    gload_lds16(bS[1] + (T) * BK, &Bs[SET][1 * 4096 + sd]);
#define STG2_B23(SET, T)                                             \
    gload_lds16(bS[2] + (T) * BK, &Bs[SET][2 * 4096 + sd]);          \
    gload_lds16(bS[3] + (T) * BK, &Bs[SET][3 * 4096 + sd]);
#define RD_A(DST, SET, HB)                                           \
    _Pragma("unroll") for (int mi = 0; mi < 4; ++mi)                 \
    _Pragma("unroll") for (int ks = 0; ks < 2; ++ks)                 \
        DST[mi][ks] = *(const short8*)&As[SET][(HB) + mi * 1024 + aoffs[ks]];
#define RD_B(DST, SET, NB)                                           \
    _Pragma("unroll") for (int ni = 0; ni < 2; ++ni)                 \
    _Pragma("unroll") for (int ks = 0; ks < 2; ++ks)                 \
        DST[ni][ks] = *(const short8*)&Bs[SET][((NB) + ni) * 1024 + boffs[ks]];
#define PH_MFMA(AF, BF, MB, NB)                                      \
    __builtin_amdgcn_s_barrier();                                    \
    asm volatile("s_waitcnt lgkmcnt(0)" ::: "memory");               \
    __builtin_amdgcn_sched_barrier(0);                               \
    __builtin_amdgcn_s_setprio(1);                                   \
    _Pragma("unroll") for (int ks = 0; ks < 2; ++ks)                 \
    _Pragma("unroll") for (int mi = 0; mi < 4; ++mi)                 \
    _Pragma("unroll") for (int ni = 0; ni < 2; ++ni)                 \
        acc[(MB) + mi][(NB) + ni] = __builtin_amdgcn_mfma_f32_16x16x32_bf16( \
            AF[mi][ks], BF[ni][ks], acc[(MB) + mi][(NB) + ni], 0, 0, 0);     \
    __builtin_amdgcn_s_setprio(0);                                   \
    __builtin_amdgcn_s_barrier();

    STG2_A01(0, 0) STG2_A23(0, 0) STG2_B01(0, 0) STG2_B23(0, 0)
    STG2_A01(1, 1) STG2_A23(1, 1) STG2_B01(1, 1) STG2_B23(1, 1)
    asm volatile("s_waitcnt vmcnt(8)" ::: "memory");
    __builtin_amdgcn_s_barrier();

#pragma unroll 1
    for (int j = 0; j < 16; ++j) {
        const int tl = 2 * j + 1;
        const int t2 = 2 * j + 2;
        const int t3 = 2 * j + 3;
        const bool s2 = (t2 < 32);
        const bool s3 = (t3 < 32);
        short8 aF[4][2], aG[4][2], b01[2][2], b23[2][2];
        RD_A(aF, 0, 0)
        RD_B(b01, 0, 0)
        if (j > 0) { STG2_A23(1, tl) }
        PH_MFMA(aF, b01, 0, 0)
        RD_B(b23, 0, 2)
        if (j > 0) { STG2_B01(1, tl) }
        PH_MFMA(aF, b23, 0, 2)
        RD_A(aG, 0, 4096)
        if (j > 0) { STG2_B23(1, tl) }
        PH_MFMA(aG, b23, 4, 2)
        if (s2) {
            STG2_A01(0, t2)
            asm volatile("s_waitcnt vmcnt(2)" ::: "memory");
        } else {
            asm volatile("s_waitcnt vmcnt(0)" ::: "memory");
        }
        PH_MFMA(aG, b01, 4, 0)
        RD_A(aF, 1, 0)
        RD_B(b01, 1, 0)
        if (s2) { STG2_A23(0, t2) }
        PH_MFMA(aF, b01, 0, 0)
        RD_B(b23, 1, 2)
        if (s2) { STG2_B01(0, t2) }
        PH_MFMA(aF, b23, 0, 2)
        RD_A(aG, 1, 4096)
        if (s2) { STG2_B23(0, t2) }
        PH_MFMA(aG, b23, 4, 2)
        if (s3) {
            STG2_A01(1, t3)
            asm volatile("s_waitcnt vmcnt(2)" ::: "memory");
        }
        PH_MFMA(aG, b01, 4, 0)
    }
#undef STG2_A01
#undef STG2_A23
#undef STG2_B01
#undef STG2_B23
#undef RD_A
#undef RD_B
#undef PH_MFMA

    unsigned short* Co = nsel ? O1 : O0;
#pragma unroll
    for (int mi = 0; mi < 8; ++mi)
#pragma unroll
        for (int ni = 0; ni < 4; ++ni) {
            const int col = nloc + wn * 64 + ni * 16 + fr;
            const float bv = bias[col];
#pragma unroll
            for (int r = 0; r < 4; ++r) {
                const int row = m0 + wm * 128 + mi * 16 + fg * 4 + r;
                Co[(size_t)row * D_MODEL + col] = f2bf(acc[mi][ni][r] + bv);
            }
        }
}

// ============ V^T GEMM (triple-buffered, grid 256 exact, unchanged) ============
__global__ __launch_bounds__(512, 2)
void gemmV(const unsigned short* __restrict__ Wv,
           const unsigned short* __restrict__ X,
           const float* __restrict__ bvf,
           unsigned short* __restrict__ VT) {
    constexpr int BK = 64;
    constexpr int K = D_MODEL;
    constexpr int NTILES = K / BK;
    constexpr int NWG = 256;
    __shared__ unsigned short As[3][128 * BK];
    __shared__ unsigned short Bs[3][256 * BK];

    const int tid  = threadIdx.x;
    const int lane = tid & 63;
    const int wid  = tid >> 6;

    const int wk = (blockIdx.x & 7) * (NWG >> 3) + (blockIdx.x >> 3);
    const int nt = wk & 15;
    const int mt = wk >> 4;
    const int m0 = mt * 128;
    const int n0 = nt * 256;

    const int srow = tid >> 3;
    const int sch  = tid & 7;
    const int ssw  = (sch ^ (srow & 7)) * 8;
    const int sd   = srow * 64 + sch * 8;
    const unsigned short* aS[2];
#pragma unroll
    for (int j = 0; j < 2; ++j) aS[j] = Wv + (size_t)(m0 + j * 64 + srow) * K + ssw;
    const unsigned short* bS[4];
#pragma unroll
    for (int j = 0; j < 4; ++j) bS[j] = X + (size_t)(n0 + j * 64 + srow) * K + ssw;

    const int fr = lane & 15, fg = lane >> 4;
    const int wm = wid >> 2, wn = wid & 3;
    int aoff[4][2], boff[4][2];
#pragma unroll
    for (int i = 0; i < 4; ++i)
#pragma unroll
        for (int ks = 0; ks < 2; ++ks) {
            const int sw = ((ks * 4 + fg) ^ (fr & 7)) * 8;
            aoff[i][ks] = (wm * 64 + i * 16 + fr) * BK + sw;
            boff[i][ks] = (wn * 64 + i * 16 + fr) * BK + sw;
        }

    f32x4 acc[4][4] = {};

    unsigned short *pA0 = As[0], *pA1 = As[1], *pA2 = As[2];
    unsigned short *pB0 = Bs[0], *pB1 = Bs[1], *pB2 = Bs[2];

#define STG_AV(P, T) { _Pragma("unroll") for (int j = 0; j < 2; ++j) \
        gload_lds16(aS[j] + (T) * BK, (P) + j * 4096 + sd); }
#define STG_BV(P, T) { _Pragma("unroll") for (int j = 0; j < 4; ++j) \
        gload_lds16(bS[j] + (T) * BK, (P) + j * 4096 + sd); }

    STG_AV(pA0, 0) STG_BV(pB0, 0)
    STG_AV(pA1, 1) STG_BV(pB1, 1)
    asm volatile("s_waitcnt vmcnt(6)" ::: "memory");
    __builtin_amdgcn_s_barrier();

#pragma unroll 1
    for (int t = 0; t < NTILES; ++t) {
        const bool more = (t + 2 < NTILES);
        short8 aF[4][2], bF0[2][2];
#pragma unroll
        for (int mi = 0; mi < 4; ++mi)
#pragma unroll
            for (int ks = 0; ks < 2; ++ks)
                aF[mi][ks] = *(const short8*)&pA0[aoff[mi][ks]];
#pragma unroll
        for (int ni = 0; ni < 2; ++ni)
#pragma unroll
            for (int ks = 0; ks < 2; ++ks)
                bF0[ni][ks] = *(const short8*)&pB0[boff[ni][ks]];
        if (more) { STG_AV(pA2, t + 2) STG_BV(pB2, t + 2) }
        asm volatile("s_waitcnt lgkmcnt(0)" ::: "memory");
        __builtin_amdgcn_sched_barrier(0);
        __builtin_amdgcn_s_setprio(1);
#pragma unroll
        for (int ks = 0; ks < 2; ++ks)
#pragma unroll
            for (int mi = 0; mi < 4; ++mi)
#pragma unroll
                for (int ni = 0; ni < 2; ++ni)
                    acc[mi][ni] = __builtin_amdgcn_mfma_f32_16x16x32_bf16(
                        aF[mi][ks], bF0[ni][ks], acc[mi][ni], 0, 0, 0);
        __builtin_amdgcn_s_setprio(0);
        short8 bG[2][2];
#pragma unroll
        for (int ni = 0; ni < 2; ++ni)
#pragma unroll
            for (int ks = 0; ks < 2; ++ks)
                bG[ni][ks] = *(const short8*)&pB0[boff[2 + ni][ks]];
        asm volatile("s_waitcnt lgkmcnt(0)" ::: "memory");
        __builtin_amdgcn_sched_barrier(0);
        __builtin_amdgcn_s_setprio(1);
#pragma unroll
        for (int ks = 0; ks < 2; ++ks)
#pragma unroll
            for (int mi = 0; mi < 4; ++mi)
#pragma unroll
                for (int ni = 0; ni < 2; ++ni)
                    acc[mi][2 + ni] = __builtin_amdgcn_mfma_f32_16x16x32_bf16(
                        aF[mi][ks], bG[ni][ks], acc[mi][2 + ni], 0, 0, 0);
        __builtin_amdgcn_s_setprio(0);
        if (more) asm volatile("s_waitcnt vmcnt(6)" ::: "memory");
        else      asm volatile("s_waitcnt vmcnt(0)" ::: "memory");
        __builtin_amdgcn_s_barrier();
        unsigned short* tA = pA0; pA0 = pA1; pA1 = pA2; pA2 = tA;
        unsigned short* tB = pB0; pB0 = pB1; pB1 = pB2; pB2 = tB;
    }
#undef STG_AV
#undef STG_BV

#pragma unroll
    for (int mi = 0; mi < 4; ++mi)
#pragma unroll
        for (int r = 0; r < 4; ++r) {
            const int row = m0 + wm * 64 + mi * 16 + fg * 4 + r;
            const float bv = bvf[row];
#pragma unroll
            for (int ni = 0; ni < 4; ++ni) {
                const int col = n0 + wn * 64 + ni * 16 + fr;
                VT[(size_t)row * MROWS + col] = f2bf(acc[mi][ni][r] + bv);
            }
        }
}

// ---------------- triple-buffer GEMM (out-projection, unchanged) ----------------
__global__ __launch_bounds__(512, 2)
void gemmT1(const unsigned short* __restrict__ A,
            const unsigned short* __restrict__ W0,
            const float* __restrict__ b0f,
            float* __restrict__ OF) {
    constexpr int BM = 256, BN = 128, BK = 64;
    constexpr int K = D_MODEL;
    constexpr int NTILES = K / BK;
    constexpr int NT_N = 16;
    constexpr int NWG = (MROWS / BM) * NT_N;
    __shared__ unsigned short As[3][BM * BK];
    __shared__ unsigned short Bs[3][BN * BK];

    const int tid  = threadIdx.x;
    const int lane = tid & 63;
    const int wid  = tid >> 6;

    const int wk = (blockIdx.x & 7) * (NWG >> 3) + (blockIdx.x >> 3);
    const int nt = wk % NT_N;
    const int mt = wk / NT_N;
    const int m0 = mt * BM;
    const int n0 = nt * BN;

    const int srow = tid >> 3;
    const int sch  = tid & 7;
    const int ssw  = (sch ^ (srow & 7)) * 8;
    const int sd   = srow * 64 + sch * 8;
    const unsigned short* aS[4];
#pragma unroll
    for (int j = 0; j < 4; ++j) aS[j] = A + (size_t)(m0 + j * 64 + srow) * K + ssw;
    const unsigned short* bS[2];
#pragma unroll
    for (int j = 0; j < 2; ++j) bS[j] = W0 + (size_t)(n0 + j * 64 + srow) * K + ssw;

    const int fr = lane & 15, fg = lane >> 4;
    const int wm = wid >> 1, wn = wid & 1;
    int aoff[4][2], boff[4][2];
#pragma unroll
    for (int mi = 0; mi < 4; ++mi)
#pragma unroll
        for (int ks = 0; ks < 2; ++ks) {
            aoff[mi][ks] = (wm * 64 + mi * 16 + fr) * BK + ((ks * 4 + fg) ^ (fr & 7)) * 8;
            boff[mi][ks] = (wn * 64 + mi * 16 + fr) * BK + ((ks * 4 + fg) ^ (fr & 7)) * 8;
        }

    f32x4 acc[4][4] = {};

    unsigned short *pA0 = As[0], *pA1 = As[1], *pA2 = As[2];
    unsigned short *pB0 = Bs[0], *pB1 = Bs[1], *pB2 = Bs[2];

#define STG_A3(P, T) { _Pragma("unroll") for (int j = 0; j < 4; ++j) \
        gload_lds16(aS[j] + (T) * BK, (P) + j * 4096 + sd); }
#define STG_B3(P, T) { _Pragma("unroll") for (int j = 0; j < 2; ++j) \
        gload_lds16(bS[j] + (T) * BK, (P) + j * 4096 + sd); }

    STG_A3(pA0, 0) STG_B3(pB0, 0)
    STG_A3(pA1, 1) STG_B3(pB1, 1)
    asm volatile("s_waitcnt vmcnt(6)" ::: "memory");
    __builtin_amdgcn_s_barrier();

#pragma unroll 1
    for (int t = 0; t < NTILES; ++t) {
        const bool more = (t + 2 < NTILES);
        short8 aF[4][2], bF0[2][2];
#pragma unroll
        for (int mi = 0; mi < 4; ++mi)
#pragma unroll
            for (int ks = 0; ks < 2; ++ks)
                aF[mi][ks] = *(const short8*)&pA0[aoff[mi][ks]];
#pragma unroll
        for (int ni = 0; ni < 2; ++ni)
#pragma unroll
            for (int ks = 0; ks < 2; ++ks)
                bF0[ni][ks] = *(const short8*)&pB0[boff[ni][ks]];
        if (more) { STG_A3(pA2, t + 2) STG_B3(pB2, t + 2) }
        asm volatile("s_waitcnt lgkmcnt(0)" ::: "memory");
        __builtin_amdgcn_sched_barrier(0);
        __builtin_amdgcn_s_setprio(1);
#pragma unroll
        for (int ks = 0; ks < 2; ++ks)
#pragma unroll
            for (int mi = 0; mi < 4; ++mi)
#pragma unroll
                for (int ni = 0; ni < 2; ++ni)
                    acc[mi][ni] = __builtin_amdgcn_mfma_f32_16x16x32_bf16(
                        aF[mi][ks], bF0[ni][ks], acc[mi][ni], 0, 0, 0);
        __builtin_amdgcn_s_setprio(0);
        short8 bG[2][2];
#pragma unroll
        for (int ni = 0; ni < 2; ++ni)
#pragma unroll
            for (int ks = 0; ks < 2; ++ks)
                bG[ni][ks] = *(const short8*)&pB0[boff[2 + ni][ks]];
        asm volatile("s_waitcnt lgkmcnt(0)" ::: "memory");
        __builtin_amdgcn_sched_barrier(0);
        __builtin_amdgcn_s_setprio(1);
#pragma unroll
        for (int ks = 0; ks < 2; ++ks)
#pragma unroll
            for (int mi = 0; mi < 4; ++mi)
#pragma unroll
                for (int ni = 0; ni < 2; ++ni)
                    acc[mi][2 + ni] = __builtin_amdgcn_mfma_f32_16x16x32_bf16(
                        aF[mi][ks], bG[ni][ks], acc[mi][2 + ni], 0, 0, 0);
        __builtin_amdgcn_s_setprio(0);
        if (more) asm volatile("s_waitcnt vmcnt(6)" ::: "memory");
        else      asm volatile("s_waitcnt vmcnt(0)" ::: "memory");
        __builtin_amdgcn_s_barrier();
        unsigned short* tA = pA0; pA0 = pA1; pA1 = pA2; pA2 = tA;
        unsigned short* tB = pB0; pB0 = pB1; pB1 = pB2; pB2 = tB;
    }
#undef STG_A3
#undef STG_B3

#pragma unroll
    for (int mi = 0; mi < 4; ++mi)
#pragma unroll
        for (int ni = 0; ni < 4; ++ni) {
            const int col = n0 + wn * 64 + ni * 16 + fr;
            const float bv = b0f[col];
#pragma unroll
            for (int r = 0; r < 4; ++r) {
                const int row = m0 + wm * 64 + mi * 16 + fg * 4 + r;
                OF[(size_t)row * D_MODEL + col] = acc[mi][ni][r] + bv;
            }
        }
}

// ======== flash attention v7: m214 geometry — 8 waves x 32q = 256 q-rows/block ====
// Grid 256 = 1 block/CU; ONE shared K/V double-buffered tile per CU (staging per
// CU halves vs v3's 2 blocks). Per-wave math identical to v3. XCD swizzle: each
// XCD gets 32 consecutive work-ids = 4 full (b,h) heads (K+V 4MB = L2).
__global__ __launch_bounds__(512, 2)
void flash_attn7(const unsigned short* __restrict__ Q, const unsigned short* __restrict__ Kg,
                 const unsigned short* __restrict__ VT, unsigned short* __restrict__ O) {
    constexpr int KVB = 64;
    constexpr int NT = SEQ / KVB;
    __shared__ unsigned short Ks[2 * KVB * DH];   // 32KB dbuf
    __shared__ unsigned short Vs[2 * DH * KVB];   // 32KB dbuf

    const int tid  = threadIdx.x;
    const int lane = tid & 63;
    const int wid  = tid >> 6;               // 0..7
    const int l31  = lane & 31;
    const int hi   = lane >> 5;

    const int swz = (blockIdx.x & 7) * 32 + (blockIdx.x >> 3);  // bijective, 256=8*32
    const int qt = swz & 7;                  // 8 q-tiles of 256 rows per (b,h)
    const int bh = swz >> 3;
    const int b = bh >> 4, h = bh & 15;
    const int qrow = qt * 256 + wid * 32 + l31;

    const unsigned short* Qp = Q + ((size_t)b * SEQ + qrow) * D_MODEL + h * DH;
    const unsigned short* Kp = Kg + (size_t)b * SEQ * D_MODEL + h * DH;
    const unsigned short* Vp = VT + (size_t)(h * DH) * MROWS + (size_t)b * SEQ;

    short8 qf[8];
#pragma unroll
    for (int kk = 0; kk < 8; ++kk)
        qf[kk] = *(const short8*)(Qp + kk * 16 + hi * 8);

    f32x16 acc[4] = {};
    float m_run = -1e30f, l_run = 0.f;
    const float Cc = 0.088388347648318447f * 1.4426950408889634f;
    const float THR = 8.0f / Cc;

    int co[8];
#pragma unroll
    for (int kk = 0; kk < 8; ++kk) co[kk] = ((kk * 2 + hi) ^ (l31 & 7)) * 8;

    // staging (8-way wave split): K 8 rows/wave (2 gloads), V 16 d-rows/wave (2 gloads)
    int kroff[2], vroff[2];
#pragma unroll
    for (int q = 0; q < 2; ++q) {
        const int row_l = wid * 8 + q * 4 + (lane >> 4);
        kroff[q] = row_l * D_MODEL + ((lane & 15) ^ (row_l & 7)) * 8;
        const int d_l = wid * 16 + q * 8 + (lane >> 3);
        vroff[q] = d_l * MROWS + ((lane & 7) ^ (d_l & 7)) * 8;
    }
    unsigned short* KsW = Ks + (wid * 8) * DH;
    unsigned short* VsW = Vs + (wid * 16) * KVB;

#pragma unroll
    for (int q = 0; q < 2; ++q) {
        gload_lds16(Kp + kroff[q], KsW + q * 4 * DH);
        gload_lds16(Vp + vroff[q], VsW + q * 8 * KVB);
    }
    __syncthreads();

#pragma unroll 1
    for (int t = 0; t < NT; ++t) {
        const int cur = t & 1;
        if (t + 1 < NT) {
            const unsigned short* Kt = Kp + (size_t)((t + 1) * KVB) * D_MODEL;
            const unsigned short* Vt = Vp + (t + 1) * KVB;
            unsigned short* kd = KsW + (cur ^ 1) * (KVB * DH);
            unsigned short* vd = VsW + (cur ^ 1) * (DH * KVB);
#pragma unroll
            for (int q = 0; q < 2; ++q) {
                gload_lds16(Kt + kroff[q], kd + q * 4 * DH);
                gload_lds16(Vt + vroff[q], vd + q * 8 * KVB);
            }
        }
        const unsigned short* Kc = Ks + cur * (KVB * DH);
        const unsigned short* Vc = Vs + cur * (DH * KVB);

        f32x16 st0 = {}, st1 = {};
        __builtin_amdgcn_s_setprio(1);
#pragma unroll
        for (int kk = 0; kk < 8; ++kk) {
            const short8 kf0 = *(const short8*)&Kc[l31 * DH + co[kk]];
            const short8 kf1 = *(const short8*)&Kc[(32 + l31) * DH + co[kk]];
            st0 = __builtin_amdgcn_mfma_f32_32x32x16_bf16(kf0, qf[kk], st0, 0, 0, 0);
            st1 = __builtin_amdgcn_mfma_f32_32x32x16_bf16(kf1, qf[kk], st1, 0, 0, 0);
        }
        __builtin_amdgcn_s_setprio(0);

        float lm = -1e30f;
#pragma unroll
        for (int r = 0; r < 16; ++r) lm = fmaxf(lm, fmaxf(st0[r], st1[r]));
        {
            unsigned int a = __builtin_bit_cast(unsigned int, lm), bb = a;
            swap32(a, bb);
            lm = fmaxf(lm, __builtin_bit_cast(float, hi ? a : bb));
        }
        if (__any(lm > m_run + THR)) {
            const float mn = fmaxf(m_run, lm);
            const float sf = __builtin_amdgcn_exp2f((m_run - mn) * Cc);
            m_run = mn;
            l_run *= sf;
#pragma unroll
            for (int db = 0; db < 4; ++db)
#pragma unroll
                for (int r = 0; r < 16; ++r) acc[db][r] *= sf;
        }
        const float mc = m_run * Cc;
        float p0[16], p1[16];
        float ps = 0.f;
#pragma unroll
        for (int r = 0; r < 16; ++r) {
            p0[r] = __builtin_amdgcn_exp2f(__builtin_fmaf(st0[r], Cc, -mc));
            p1[r] = __builtin_amdgcn_exp2f(__builtin_fmaf(st1[r], Cc, -mc));
            ps += p0[r] + p1[r];
        }
        {
            unsigned int a = __builtin_bit_cast(unsigned int, ps), bb = a;
            swap32(a, bb);
            ps += __builtin_bit_cast(float, hi ? a : bb);
        }
        l_run += ps;

        unsigned int W0[8], W1[8];
#pragma unroll
        for (int tt = 0; tt < 8; ++tt) {
            W0[tt] = cvt_pk_bf16(p0[2 * tt], p0[2 * tt + 1]);
            W1[tt] = cvt_pk_bf16(p1[2 * tt], p1[2 * tt + 1]);
        }
        swap32(W0[0], W0[2]); swap32(W0[1], W0[3]);
        swap32(W0[4], W0[6]); swap32(W0[5], W0[7]);
        swap32(W1[0], W1[2]); swap32(W1[1], W1[3]);
        swap32(W1[4], W1[6]); swap32(W1[5], W1[7]);
        short8 pf[4];
        {
            uint4 f;
            f.x = W0[0]; f.y = W0[1]; f.z = W0[2]; f.w = W0[3];
            pf[0] = __builtin_bit_cast(short8, f);
            f.x = W0[4]; f.y = W0[5]; f.z = W0[6]; f.w = W0[7];
            pf[1] = __builtin_bit_cast(short8, f);
            f.x = W1[0]; f.y = W1[1]; f.z = W1[2]; f.w = W1[3];
            pf[2] = __builtin_bit_cast(short8, f);
            f.x = W1[4]; f.y = W1[5]; f.z = W1[6]; f.w = W1[7];
            pf[3] = __builtin_bit_cast(short8, f);
        }

        __builtin_amdgcn_s_setprio(1);
#pragma unroll
        for (int db = 0; db < 4; ++db) {
#pragma unroll
            for (int kk16 = 0; kk16 < 4; ++kk16) {
                const short8 vf = *(const short8*)&Vc[(db * 32 + l31) * KVB + co[kk16]];
                acc[db] = __builtin_amdgcn_mfma_f32_32x32x16_bf16(vf, pf[kk16], acc[db], 0, 0, 0);
            }
        }
        __builtin_amdgcn_s_setprio(0);
        __syncthreads();
    }

    const float inv_l = 1.0f / l_run;
    unsigned short* Op = O + ((size_t)b * SEQ + qrow) * D_MODEL + h * DH;
#pragma unroll
    for (int db = 0; db < 4; ++db)
#pragma unroll
        for (int g = 0; g < 4; ++g) {
            ushort4 o4;
            o4.x = f2bf(acc[db][4 * g + 0] * inv_l);
            o4.y = f2bf(acc[db][4 * g + 1] * inv_l);
            o4.z = f2bf(acc[db][4 * g + 2] * inv_l);
            o4.w = f2bf(acc[db][4 * g + 3] * inv_l);
            *(ushort4*)(Op + db * 32 + g * 8 + hi * 4) = o4;
        }
}

// ---------------- host launch ----------------
extern "C" void kernel_launch(void* const* d_in, const int* in_sizes, int n_in,
                              void* d_out, int out_size, void* d_ws, size_t ws_size,
                              hipStream_t stream) {
    (void)in_sizes; (void)n_in; (void)out_size; (void)ws_size;
    const float* x  = (const float*)d_in[0];
    const float* wq = (const float*)d_in[1];
    const float* bq = (const float*)d_in[2];
    const float* wk = (const float*)d_in[3];
    const float* bk = (const float*)d_in[4];
    const float* wv = (const float*)d_in[5];
    const float* bv = (const float*)d_in[6];
    const float* wo = (const float*)d_in[7];
    const float* bo = (const float*)d_in[8];
    float* out = (float*)d_out;

    unsigned short* ws = (unsigned short*)d_ws;
    const size_t NX = (size_t)MROWS * D_MODEL;
    const size_t NW = (size_t)D_MODEL * D_MODEL;
    unsigned short* xb  = ws;
    unsigned short* wqb = xb + NX;
    unsigned short* wkb = wqb + NW;
    unsigned short* wvb = wkb + NW;
    unsigned short* wob = wvb + NW;
    unsigned short* Qb  = wob + NW;
    unsigned short* Kb  = Qb + NX;
    unsigned short* VTb = Kb + NX;   // V^T: [D_MODEL][MROWS]
    unsigned short* Ab  = VTb + NX;

    const unsigned cvt_blocks = (unsigned)((NX + 4 * NW) / 1024);  // 24576
    cvt_all<<<cvt_blocks, 256, 0, stream>>>(x, wq, wk, wv, wo, xb);

    gemm8qk<<<256, 512, 0, stream>>>(xb, wqb, wkb, bq, bk, Qb, Kb);
    gemmV<<<256, 512, 0, stream>>>(wvb, xb, bv, VTb);

    flash_attn7<<<256, 512, 0, stream>>>(Qb, Kb, VTb, Ab);

    gemmT1<<<256, 512, 0, stream>>>(Ab, wob, bo, out);
}

// Round 18
// 240.899 us; speedup vs baseline: 1.0096x; 1.0096x over previous
//
#include <hip/hip_runtime.h>
#include <cstdint>
#include <cstddef>

#define D_MODEL 2048
#define SEQ 2048
#define BATCH 2
#define HEADS 16
#define DH 128
#define MROWS (BATCH * SEQ) /* 4096 */

typedef __attribute__((ext_vector_type(8))) short short8;
typedef __attribute__((ext_vector_type(4))) float f32x4;
typedef __attribute__((ext_vector_type(16))) float f32x16;
typedef __attribute__((ext_vector_type(2))) unsigned int uint2e;

__device__ __forceinline__ unsigned short f2bf(float f) {
    unsigned int u = __builtin_bit_cast(unsigned int, f);
    u += 0x7fffu + ((u >> 16) & 1u);   // round-to-nearest-even
    return (unsigned short)(u >> 16);
}

__device__ __forceinline__ unsigned int cvt_pk_bf16(float lo, float hi) {
    unsigned int w;
    asm("v_cvt_pk_bf16_f32 %0, %1, %2" : "=v"(w) : "v"(lo), "v"(hi));
    return w;
}

__device__ __forceinline__ void swap32(unsigned int& x, unsigned int& y) {
#if __has_builtin(__builtin_amdgcn_permlane32_swap)
    uint2e r = __builtin_amdgcn_permlane32_swap(x, y, false, false);
    x = r[0]; y = r[1];
#else
    const int hi = (threadIdx.x >> 5) & 1;
    const unsigned int gx = (unsigned int)__shfl_xor((int)x, 32);
    const unsigned int gy = (unsigned int)__shfl_xor((int)y, 32);
    const unsigned int nx = hi ? gy : x;
    const unsigned int ny = hi ? y : gx;
    x = nx; y = ny;
#endif
}

__device__ __forceinline__ void gload_lds16(const unsigned short* g, unsigned short* l) {
    __builtin_amdgcn_global_load_lds(
        (const __attribute__((address_space(1))) void*)g,
        (__attribute__((address_space(3))) void*)l, 16, 0, 0);
}

// ---------------- fused fp32 -> bf16 conversion (x + 4 weights, one launch) ------
__global__ __launch_bounds__(256) void cvt_all(const float* __restrict__ x,
                                               const float* __restrict__ wq,
                                               const float* __restrict__ wk,
                                               const float* __restrict__ wv,
                                               const float* __restrict__ wo,
                                               unsigned short* __restrict__ out) {
    constexpr int PX = (MROWS * D_MODEL) / 4;
    constexpr int PW = (D_MODEL * D_MODEL) / 4;
    int i = blockIdx.x * 256 + threadIdx.x;
    const float* s;
    int off;
    if (i < PX) { s = x; off = i; }
    else {
        const int j = i - PX;
        const int sel = j / PW;
        off = j - sel * PW;
        s = sel == 0 ? wq : sel == 1 ? wk : sel == 2 ? wv : wo;
    }
    const float4 v = reinterpret_cast<const float4*>(s)[off];
    ushort4 o;
    o.x = f2bf(v.x); o.y = f2bf(v.y); o.z = f2bf(v.z); o.w = f2bf(v.w);
    reinterpret_cast<ushort4*>(out)[i] = o;
}

// ============ 8-phase 256x256 GEMM for Q+K — SPREAD-LOAD schedule ============
// 2 gloads per phase, counted vmcnt(2) at ph3/ph7. Grid 256 exact, XCD-swizzled.
__global__ __launch_bounds__(512, 2)
void gemm8qk(const unsigned short* __restrict__ A,
             const unsigned short* __restrict__ W0,
             const unsigned short* __restrict__ W1,
             const float* __restrict__ b0f,
             const float* __restrict__ b1f,
             unsigned short* __restrict__ O0,
             unsigned short* __restrict__ O1) {
    constexpr int BK = 64;
    constexpr int K = D_MODEL;
    constexpr int NT_N = 16;
    constexpr int NWG = 16 * NT_N;           // 256
    __shared__ unsigned short As[2][16384];
    __shared__ unsigned short Bs[2][16384];

    const int tid  = threadIdx.x;
    const int lane = tid & 63;
    const int wid  = tid >> 6;

    const int wk = (blockIdx.x & 7) * (NWG >> 3) + (blockIdx.x >> 3);
    const int nt = wk % NT_N;
    const int mt = wk / NT_N;
    const int m0 = mt * 256;
    const int nsel = nt >> 3;
    const int nloc = (nt & 7) * 256;

    const unsigned short* Bw = nsel ? W1 : W0;
    const float* bias = nsel ? b1f : b0f;

    const int srow = tid >> 3;
    const int sch  = tid & 7;
    const int ssw  = (sch ^ (srow & 7)) * 8;
    const int sd   = srow * 64 + sch * 8;
    const unsigned short* aS[4];
    const unsigned short* bS[4];
#pragma unroll
    for (int j = 0; j < 4; ++j) {
        aS[j] = A  + (size_t)(m0 + j * 64 + srow) * K + ssw;
        bS[j] = Bw + (size_t)(nloc + j * 64 + srow) * K + ssw;
    }

    const int fr = lane & 15, fg = lane >> 4;
    const int wm = wid >> 2, wn = wid & 3;
    int aoffs[2], boffs[2];
#pragma unroll
    for (int ks = 0; ks < 2; ++ks) {
        const int sw = ((ks * 4 + fg) ^ (fr & 7)) * 8;
        aoffs[ks] = (wm * 128 + fr) * 64 + sw;
        boffs[ks] = (wn * 64 + fr) * 64 + sw;
    }

    f32x4 acc[8][4] = {};

#define STG2_A01(SET, T)                                             \
    gload_lds16(aS[0] + (T) * BK, &As[SET][0 * 4096 + sd]);          \
    gload_lds16(aS[1] + (T) * BK, &As[SET][1 * 4096 + sd]);
#define STG2_A23(SET, T)                                             \
    gload_lds16(aS[2] + (T) * BK, &As[SET][2 * 4096 + sd]);          \
    gload_lds16(aS[3] + (T) * BK, &As[SET][3 * 4096 + sd]);
#define STG2_B01(SET, T)                                             \
    gload_lds16(bS[0] + (T) * BK, &Bs[SET][0 * 4096 + sd]);          \
    gload_lds16(bS[1] + (T) * BK, &Bs[SET][1 * 4096 + sd]);
#define STG2_B23(SET, T)                                             \
    gload_lds16(bS[2] + (T) * BK, &Bs[SET][2 * 4096 + sd]);          \
    gload_lds16(bS[3] + (T) * BK, &Bs[SET][3 * 4096 + sd]);
#define RD_A(DST, SET, HB)                                           \
    _Pragma("unroll") for (int mi = 0; mi < 4; ++mi)                 \
    _Pragma("unroll") for (int ks = 0; ks < 2; ++ks)                 \
        DST[mi][ks] = *(const short8*)&As[SET][(HB) + mi * 1024 + aoffs[ks]];
#define RD_B(DST, SET, NB)                                           \
    _Pragma("unroll") for (int ni = 0; ni < 2; ++ni)                 \
    _Pragma("unroll") for (int ks = 0; ks < 2; ++ks)                 \
        DST[ni][ks] = *(const short8*)&Bs[SET][((NB) + ni) * 1024 + boffs[ks]];
#define PH_MFMA(AF, BF, MB, NB)                                      \
    __builtin_amdgcn_s_barrier();                                    \
    asm volatile("s_waitcnt lgkmcnt(0)" ::: "memory");               \
    __builtin_amdgcn_sched_barrier(0);                               \
    __builtin_amdgcn_s_setprio(1);                                   \
    _Pragma("unroll") for (int ks = 0; ks < 2; ++ks)                 \
    _Pragma("unroll") for (int mi = 0; mi < 4; ++mi)                 \
    _Pragma("unroll") for (int ni = 0; ni < 2; ++ni)                 \
        acc[(MB) + mi][(NB) + ni] = __builtin_amdgcn_mfma_f32_16x16x32_bf16( \
            AF[mi][ks], BF[ni][ks], acc[(MB) + mi][(NB) + ni], 0, 0, 0);     \
    __builtin_amdgcn_s_setprio(0);                                   \
    __builtin_amdgcn_s_barrier();

    STG2_A01(0, 0) STG2_A23(0, 0) STG2_B01(0, 0) STG2_B23(0, 0)
    STG2_A01(1, 1) STG2_A23(1, 1) STG2_B01(1, 1) STG2_B23(1, 1)
    asm volatile("s_waitcnt vmcnt(8)" ::: "memory");
    __builtin_amdgcn_s_barrier();

#pragma unroll 1
    for (int j = 0; j < 16; ++j) {
        const int tl = 2 * j + 1;
        const int t2 = 2 * j + 2;
        const int t3 = 2 * j + 3;
        const bool s2 = (t2 < 32);
        const bool s3 = (t3 < 32);
        short8 aF[4][2], aG[4][2], b01[2][2], b23[2][2];
        RD_A(aF, 0, 0)
        RD_B(b01, 0, 0)
        if (j > 0) { STG2_A23(1, tl) }
        PH_MFMA(aF, b01, 0, 0)
        RD_B(b23, 0, 2)
        if (j > 0) { STG2_B01(1, tl) }
        PH_MFMA(aF, b23, 0, 2)
        RD_A(aG, 0, 4096)
        if (j > 0) { STG2_B23(1, tl) }
        PH_MFMA(aG, b23, 4, 2)
        if (s2) {
            STG2_A01(0, t2)
            asm volatile("s_waitcnt vmcnt(2)" ::: "memory");
        } else {
            asm volatile("s_waitcnt vmcnt(0)" ::: "memory");
        }
        PH_MFMA(aG, b01, 4, 0)
        RD_A(aF, 1, 0)
        RD_B(b01, 1, 0)
        if (s2) { STG2_A23(0, t2) }
        PH_MFMA(aF, b01, 0, 0)
        RD_B(b23, 1, 2)
        if (s2) { STG2_B01(0, t2) }
        PH_MFMA(aF, b23, 0, 2)
        RD_A(aG, 1, 4096)
        if (s2) { STG2_B23(0, t2) }
        PH_MFMA(aG, b23, 4, 2)
        if (s3) {
            STG2_A01(1, t3)
            asm volatile("s_waitcnt vmcnt(2)" ::: "memory");
        }
        PH_MFMA(aG, b01, 4, 0)
    }
#undef STG2_A01
#undef STG2_A23
#undef STG2_B01
#undef STG2_B23
#undef RD_A
#undef RD_B
#undef PH_MFMA

    unsigned short* Co = nsel ? O1 : O0;
#pragma unroll
    for (int mi = 0; mi < 8; ++mi)
#pragma unroll
        for (int ni = 0; ni < 4; ++ni) {
            const int col = nloc + wn * 64 + ni * 16 + fr;
            const float bv = bias[col];
#pragma unroll
            for (int r = 0; r < 4; ++r) {
                const int row = m0 + wm * 128 + mi * 16 + fg * 4 + r;
                Co[(size_t)row * D_MODEL + col] = f2bf(acc[mi][ni][r] + bv);
            }
        }
}

// ============ V^T GEMM (triple-buffered, grid 256 exact) ============
__global__ __launch_bounds__(512, 2)
void gemmV(const unsigned short* __restrict__ Wv,
           const unsigned short* __restrict__ X,
           const float* __restrict__ bvf,
           unsigned short* __restrict__ VT) {
    constexpr int BK = 64;
    constexpr int K = D_MODEL;
    constexpr int NTILES = K / BK;
    constexpr int NWG = 256;
    __shared__ unsigned short As[3][128 * BK];
    __shared__ unsigned short Bs[3][256 * BK];

    const int tid  = threadIdx.x;
    const int lane = tid & 63;
    const int wid  = tid >> 6;

    const int wk = (blockIdx.x & 7) * (NWG >> 3) + (blockIdx.x >> 3);
    const int nt = wk & 15;
    const int mt = wk >> 4;
    const int m0 = mt * 128;
    const int n0 = nt * 256;

    const int srow = tid >> 3;
    const int sch  = tid & 7;
    const int ssw  = (sch ^ (srow & 7)) * 8;
    const int sd   = srow * 64 + sch * 8;
    const unsigned short* aS[2];
#pragma unroll
    for (int j = 0; j < 2; ++j) aS[j] = Wv + (size_t)(m0 + j * 64 + srow) * K + ssw;
    const unsigned short* bS[4];
#pragma unroll
    for (int j = 0; j < 4; ++j) bS[j] = X + (size_t)(n0 + j * 64 + srow) * K + ssw;

    const int fr = lane & 15, fg = lane >> 4;
    const int wm = wid >> 2, wn = wid & 3;
    int aoff[4][2], boff[4][2];
#pragma unroll
    for (int i = 0; i < 4; ++i)
#pragma unroll
        for (int ks = 0; ks < 2; ++ks) {
            const int sw = ((ks * 4 + fg) ^ (fr & 7)) * 8;
            aoff[i][ks] = (wm * 64 + i * 16 + fr) * BK + sw;
            boff[i][ks] = (wn * 64 + i * 16 + fr) * BK + sw;
        }

    f32x4 acc[4][4] = {};

    unsigned short *pA0 = As[0], *pA1 = As[1], *pA2 = As[2];
    unsigned short *pB0 = Bs[0], *pB1 = Bs[1], *pB2 = Bs[2];

#define STG_AV(P, T) { _Pragma("unroll") for (int j = 0; j < 2; ++j) \
        gload_lds16(aS[j] + (T) * BK, (P) + j * 4096 + sd); }
#define STG_BV(P, T) { _Pragma("unroll") for (int j = 0; j < 4; ++j) \
        gload_lds16(bS[j] + (T) * BK, (P) + j * 4096 + sd); }

    STG_AV(pA0, 0) STG_BV(pB0, 0)
    STG_AV(pA1, 1) STG_BV(pB1, 1)
    asm volatile("s_waitcnt vmcnt(6)" ::: "memory");
    __builtin_amdgcn_s_barrier();

#pragma unroll 1
    for (int t = 0; t < NTILES; ++t) {
        const bool more = (t + 2 < NTILES);
        short8 aF[4][2], bF0[2][2];
#pragma unroll
        for (int mi = 0; mi < 4; ++mi)
#pragma unroll
            for (int ks = 0; ks < 2; ++ks)
                aF[mi][ks] = *(const short8*)&pA0[aoff[mi][ks]];
#pragma unroll
        for (int ni = 0; ni < 2; ++ni)
#pragma unroll
            for (int ks = 0; ks < 2; ++ks)
                bF0[ni][ks] = *(const short8*)&pB0[boff[ni][ks]];
        if (more) { STG_AV(pA2, t + 2) STG_BV(pB2, t + 2) }
        asm volatile("s_waitcnt lgkmcnt(0)" ::: "memory");
        __builtin_amdgcn_sched_barrier(0);
        __builtin_amdgcn_s_setprio(1);
#pragma unroll
        for (int ks = 0; ks < 2; ++ks)
#pragma unroll
            for (int mi = 0; mi < 4; ++mi)
#pragma unroll
                for (int ni = 0; ni < 2; ++ni)
                    acc[mi][ni] = __builtin_amdgcn_mfma_f32_16x16x32_bf16(
                        aF[mi][ks], bF0[ni][ks], acc[mi][ni], 0, 0, 0);
        __builtin_amdgcn_s_setprio(0);
        short8 bG[2][2];
#pragma unroll
        for (int ni = 0; ni < 2; ++ni)
#pragma unroll
            for (int ks = 0; ks < 2; ++ks)
                bG[ni][ks] = *(const short8*)&pB0[boff[2 + ni][ks]];
        asm volatile("s_waitcnt lgkmcnt(0)" ::: "memory");
        __builtin_amdgcn_sched_barrier(0);
        __builtin_amdgcn_s_setprio(1);
#pragma unroll
        for (int ks = 0; ks < 2; ++ks)
#pragma unroll
            for (int mi = 0; mi < 4; ++mi)
#pragma unroll
                for (int ni = 0; ni < 2; ++ni)
                    acc[mi][2 + ni] = __builtin_amdgcn_mfma_f32_16x16x32_bf16(
                        aF[mi][ks], bG[ni][ks], acc[mi][2 + ni], 0, 0, 0);
        __builtin_amdgcn_s_setprio(0);
        if (more) asm volatile("s_waitcnt vmcnt(6)" ::: "memory");
        else      asm volatile("s_waitcnt vmcnt(0)" ::: "memory");
        __builtin_amdgcn_s_barrier();
        unsigned short* tA = pA0; pA0 = pA1; pA1 = pA2; pA2 = tA;
        unsigned short* tB = pB0; pB0 = pB1; pB1 = pB2; pB2 = tB;
    }
#undef STG_AV
#undef STG_BV

#pragma unroll
    for (int mi = 0; mi < 4; ++mi)
#pragma unroll
        for (int r = 0; r < 4; ++r) {
            const int row = m0 + wm * 64 + mi * 16 + fg * 4 + r;
            const float bv = bvf[row];
#pragma unroll
            for (int ni = 0; ni < 4; ++ni) {
                const int col = n0 + wn * 64 + ni * 16 + fr;
                VT[(size_t)row * MROWS + col] = f2bf(acc[mi][ni][r] + bv);
            }
        }
}

// ---------------- triple-buffer GEMM (out-projection) ----------------
__global__ __launch_bounds__(512, 2)
void gemmT1(const unsigned short* __restrict__ A,
            const unsigned short* __restrict__ W0,
            const float* __restrict__ b0f,
            float* __restrict__ OF) {
    constexpr int BM = 256, BN = 128, BK = 64;
    constexpr int K = D_MODEL;
    constexpr int NTILES = K / BK;
    constexpr int NT_N = 16;
    constexpr int NWG = (MROWS / BM) * NT_N;
    __shared__ unsigned short As[3][BM * BK];
    __shared__ unsigned short Bs[3][BN * BK];

    const int tid  = threadIdx.x;
    const int lane = tid & 63;
    const int wid  = tid >> 6;

    const int wk = (blockIdx.x & 7) * (NWG >> 3) + (blockIdx.x >> 3);
    const int nt = wk % NT_N;
    const int mt = wk / NT_N;
    const int m0 = mt * BM;
    const int n0 = nt * BN;

    const int srow = tid >> 3;
    const int sch  = tid & 7;
    const int ssw  = (sch ^ (srow & 7)) * 8;
    const int sd   = srow * 64 + sch * 8;
    const unsigned short* aS[4];
#pragma unroll
    for (int j = 0; j < 4; ++j) aS[j] = A + (size_t)(m0 + j * 64 + srow) * K + ssw;
    const unsigned short* bS[2];
#pragma unroll
    for (int j = 0; j < 2; ++j) bS[j] = W0 + (size_t)(n0 + j * 64 + srow) * K + ssw;

    const int fr = lane & 15, fg = lane >> 4;
    const int wm = wid >> 1, wn = wid & 1;
    int aoff[4][2], boff[4][2];
#pragma unroll
    for (int mi = 0; mi < 4; ++mi)
#pragma unroll
        for (int ks = 0; ks < 2; ++ks) {
            aoff[mi][ks] = (wm * 64 + mi * 16 + fr) * BK + ((ks * 4 + fg) ^ (fr & 7)) * 8;
            boff[mi][ks] = (wn * 64 + mi * 16 + fr) * BK + ((ks * 4 + fg) ^ (fr & 7)) * 8;
        }

    f32x4 acc[4][4] = {};

    unsigned short *pA0 = As[0], *pA1 = As[1], *pA2 = As[2];
    unsigned short *pB0 = Bs[0], *pB1 = Bs[1], *pB2 = Bs[2];

#define STG_A3(P, T) { _Pragma("unroll") for (int j = 0; j < 4; ++j) \
        gload_lds16(aS[j] + (T) * BK, (P) + j * 4096 + sd); }
#define STG_B3(P, T) { _Pragma("unroll") for (int j = 0; j < 2; ++j) \
        gload_lds16(bS[j] + (T) * BK, (P) + j * 4096 + sd); }

    STG_A3(pA0, 0) STG_B3(pB0, 0)
    STG_A3(pA1, 1) STG_B3(pB1, 1)
    asm volatile("s_waitcnt vmcnt(6)" ::: "memory");
    __builtin_amdgcn_s_barrier();

#pragma unroll 1
    for (int t = 0; t < NTILES; ++t) {
        const bool more = (t + 2 < NTILES);
        short8 aF[4][2], bF0[2][2];
#pragma unroll
        for (int mi = 0; mi < 4; ++mi)
#pragma unroll
            for (int ks = 0; ks < 2; ++ks)
                aF[mi][ks] = *(const short8*)&pA0[aoff[mi][ks]];
#pragma unroll
        for (int ni = 0; ni < 2; ++ni)
#pragma unroll
            for (int ks = 0; ks < 2; ++ks)
                bF0[ni][ks] = *(const short8*)&pB0[boff[ni][ks]];
        if (more) { STG_A3(pA2, t + 2) STG_B3(pB2, t + 2) }
        asm volatile("s_waitcnt lgkmcnt(0)" ::: "memory");
        __builtin_amdgcn_sched_barrier(0);
        __builtin_amdgcn_s_setprio(1);
#pragma unroll
        for (int ks = 0; ks < 2; ++ks)
#pragma unroll
            for (int mi = 0; mi < 4; ++mi)
#pragma unroll
                for (int ni = 0; ni < 2; ++ni)
                    acc[mi][ni] = __builtin_amdgcn_mfma_f32_16x16x32_bf16(
                        aF[mi][ks], bF0[ni][ks], acc[mi][ni], 0, 0, 0);
        __builtin_amdgcn_s_setprio(0);
        short8 bG[2][2];
#pragma unroll
        for (int ni = 0; ni < 2; ++ni)
#pragma unroll
            for (int ks = 0; ks < 2; ++ks)
                bG[ni][ks] = *(const short8*)&pB0[boff[2 + ni][ks]];
        asm volatile("s_waitcnt lgkmcnt(0)" ::: "memory");
        __builtin_amdgcn_sched_barrier(0);
        __builtin_amdgcn_s_setprio(1);
#pragma unroll
        for (int ks = 0; ks < 2; ++ks)
#pragma unroll
            for (int mi = 0; mi < 4; ++mi)
#pragma unroll
                for (int ni = 0; ni < 2; ++ni)
                    acc[mi][2 + ni] = __builtin_amdgcn_mfma_f32_16x16x32_bf16(
                        aF[mi][ks], bG[ni][ks], acc[mi][2 + ni], 0, 0, 0);
        __builtin_amdgcn_s_setprio(0);
        if (more) asm volatile("s_waitcnt vmcnt(6)" ::: "memory");
        else      asm volatile("s_waitcnt vmcnt(0)" ::: "memory");
        __builtin_amdgcn_s_barrier();
        unsigned short* tA = pA0; pA0 = pA1; pA1 = pA2; pA2 = tA;
        unsigned short* tB = pB0; pB0 = pB1; pB1 = pB2; pB2 = tB;
    }
#undef STG_A3
#undef STG_B3

#pragma unroll
    for (int mi = 0; mi < 4; ++mi)
#pragma unroll
        for (int ni = 0; ni < 4; ++ni) {
            const int col = n0 + wn * 64 + ni * 16 + fr;
            const float bv = b0f[col];
#pragma unroll
            for (int r = 0; r < 4; ++r) {
                const int row = m0 + wm * 64 + mi * 16 + fg * 4 + r;
                OF[(size_t)row * D_MODEL + col] = acc[mi][ni][r] + bv;
            }
        }
}

// ---------------- flash attention v3 + XCD-chunked block swizzle ----------------
__global__ __launch_bounds__(256, 2)
void flash_attn3(const unsigned short* __restrict__ Q, const unsigned short* __restrict__ Kg,
                 const unsigned short* __restrict__ VT, unsigned short* __restrict__ O) {
    constexpr int KVB = 64;
    constexpr int NT = SEQ / KVB;
    __shared__ unsigned short Ks[2 * KVB * DH];
    __shared__ unsigned short Vs[2 * DH * KVB];

    const int tid  = threadIdx.x;
    const int lane = tid & 63;
    const int wid  = tid >> 6;
    const int l31  = lane & 31;
    const int hi   = lane >> 5;

    const int swz = (blockIdx.x & 7) * 64 + (blockIdx.x >> 3);
    const int qt = swz & 15;
    const int bh = swz >> 4;
    const int b = bh >> 4, h = bh & 15;
    const int qrow = qt * 128 + wid * 32 + l31;

    const unsigned short* Qp = Q + ((size_t)b * SEQ + qrow) * D_MODEL + h * DH;
    const unsigned short* Kp = Kg + (size_t)b * SEQ * D_MODEL + h * DH;
    const unsigned short* Vp = VT + (size_t)(h * DH) * MROWS + (size_t)b * SEQ;

    short8 qf[8];
#pragma unroll
    for (int kk = 0; kk < 8; ++kk)
        qf[kk] = *(const short8*)(Qp + kk * 16 + hi * 8);

    f32x16 acc[4] = {};
    float m_run = -1e30f, l_run = 0.f;
    const float Cc = 0.088388347648318447f * 1.4426950408889634f;
    const float THR = 8.0f / Cc;

    int co[8];
#pragma unroll
    for (int kk = 0; kk < 8; ++kk) co[kk] = ((kk * 2 + hi) ^ (l31 & 7)) * 8;

    int kroff[4], vroff[4];
#pragma unroll
    for (int q = 0; q < 4; ++q) {
        const int row_l = wid * 16 + q * 4 + (lane >> 4);
        kroff[q] = row_l * D_MODEL + ((lane & 15) ^ (row_l & 7)) * 8;
        const int d_l = wid * 32 + q * 8 + (lane >> 3);
        vroff[q] = d_l * MROWS + ((lane & 7) ^ (d_l & 7)) * 8;
    }
    unsigned short* KsW = Ks + (wid * 16) * DH;
    unsigned short* VsW = Vs + (wid * 32) * KVB;

#pragma unroll
    for (int q = 0; q < 4; ++q) {
        gload_lds16(Kp + kroff[q], KsW + q * 4 * DH);
        gload_lds16(Vp + vroff[q], VsW + q * 8 * KVB);
    }
    __syncthreads();

#pragma unroll 1
    for (int t = 0; t < NT; ++t) {
        const int cur = t & 1;
        if (t + 1 < NT) {
            const unsigned short* Kt = Kp + (size_t)((t + 1) * KVB) * D_MODEL;
            const unsigned short* Vt = Vp + (t + 1) * KVB;
            unsigned short* kd = KsW + (cur ^ 1) * (KVB * DH);
            unsigned short* vd = VsW + (cur ^ 1) * (DH * KVB);
#pragma unroll
            for (int q = 0; q < 4; ++q) {
                gload_lds16(Kt + kroff[q], kd + q * 4 * DH);
                gload_lds16(Vt + vroff[q], vd + q * 8 * KVB);
            }
        }
        const unsigned short* Kc = Ks + cur * (KVB * DH);
        const unsigned short* Vc = Vs + cur * (DH * KVB);

        f32x16 st0 = {}, st1 = {};
        __builtin_amdgcn_s_setprio(1);
#pragma unroll
        for (int kk = 0; kk < 8; ++kk) {
            const short8 kf0 = *(const short8*)&Kc[l31 * DH + co[kk]];
            const short8 kf1 = *(const short8*)&Kc[(32 + l31) * DH + co[kk]];
            st0 = __builtin_amdgcn_mfma_f32_32x32x16_bf16(kf0, qf[kk], st0, 0, 0, 0);
            st1 = __builtin_amdgcn_mfma_f32_32x32x16_bf16(kf1, qf[kk], st1, 0, 0, 0);
        }
        __builtin_amdgcn_s_setprio(0);

        float lm = -1e30f;
#pragma unroll
        for (int r = 0; r < 16; ++r) lm = fmaxf(lm, fmaxf(st0[r], st1[r]));
        {
            unsigned int a = __builtin_bit_cast(unsigned int, lm), bb = a;
            swap32(a, bb);
            lm = fmaxf(lm, __builtin_bit_cast(float, hi ? a : bb));
        }
        if (__any(lm > m_run + THR)) {
            const float mn = fmaxf(m_run, lm);
            const float sf = __builtin_amdgcn_exp2f((m_run - mn) * Cc);
            m_run = mn;
            l_run *= sf;
#pragma unroll
            for (int db = 0; db < 4; ++db)
#pragma unroll
                for (int r = 0; r < 16; ++r) acc[db][r] *= sf;
        }
        const float mc = m_run * Cc;
        float p0[16], p1[16];
        float ps = 0.f;
#pragma unroll
        for (int r = 0; r < 16; ++r) {
            p0[r] = __builtin_amdgcn_exp2f(__builtin_fmaf(st0[r], Cc, -mc));
            p1[r] = __builtin_amdgcn_exp2f(__builtin_fmaf(st1[r], Cc, -mc));
            ps += p0[r] + p1[r];
        }
        {
            unsigned int a = __builtin_bit_cast(unsigned int, ps), bb = a;
            swap32(a, bb);
            ps += __builtin_bit_cast(float, hi ? a : bb);
        }
        l_run += ps;

        unsigned int W0[8], W1[8];
#pragma unroll
        for (int tt = 0; tt < 8; ++tt) {
            W0[tt] = cvt_pk_bf16(p0[2 * tt], p0[2 * tt + 1]);
            W1[tt] = cvt_pk_bf16(p1[2 * tt], p1[2 * tt + 1]);
        }
        swap32(W0[0], W0[2]); swap32(W0[1], W0[3]);
        swap32(W0[4], W0[6]); swap32(W0[5], W0[7]);
        swap32(W1[0], W1[2]); swap32(W1[1], W1[3]);
        swap32(W1[4], W1[6]); swap32(W1[5], W1[7]);
        short8 pf[4];
        {
            uint4 f;
            f.x = W0[0]; f.y = W0[1]; f.z = W0[2]; f.w = W0[3];
            pf[0] = __builtin_bit_cast(short8, f);
            f.x = W0[4]; f.y = W0[5]; f.z = W0[6]; f.w = W0[7];
            pf[1] = __builtin_bit_cast(short8, f);
            f.x = W1[0]; f.y = W1[1]; f.z = W1[2]; f.w = W1[3];
            pf[2] = __builtin_bit_cast(short8, f);
            f.x = W1[4]; f.y = W1[5]; f.z = W1[6]; f.w = W1[7];
            pf[3] = __builtin_bit_cast(short8, f);
        }

        __builtin_amdgcn_s_setprio(1);
#pragma unroll
        for (int db = 0; db < 4; ++db) {
#pragma unroll
            for (int kk16 = 0; kk16 < 4; ++kk16) {
                const short8 vf = *(const short8*)&Vc[(db * 32 + l31) * KVB + co[kk16]];
                acc[db] = __builtin_amdgcn_mfma_f32_32x32x16_bf16(vf, pf[kk16], acc[db], 0, 0, 0);
            }
        }
        __builtin_amdgcn_s_setprio(0);
        __syncthreads();
    }

    const float inv_l = 1.0f / l_run;
    unsigned short* Op = O + ((size_t)b * SEQ + qrow) * D_MODEL + h * DH;
#pragma unroll
    for (int db = 0; db < 4; ++db)
#pragma unroll
        for (int g = 0; g < 4; ++g) {
            ushort4 o4;
            o4.x = f2bf(acc[db][4 * g + 0] * inv_l);
            o4.y = f2bf(acc[db][4 * g + 1] * inv_l);
            o4.z = f2bf(acc[db][4 * g + 2] * inv_l);
            o4.w = f2bf(acc[db][4 * g + 3] * inv_l);
            *(ushort4*)(Op + db * 32 + g * 8 + hi * 4) = o4;
        }
}

// ---------------- host launch ----------------
extern "C" void kernel_launch(void* const* d_in, const int* in_sizes, int n_in,
                              void* d_out, int out_size, void* d_ws, size_t ws_size,
                              hipStream_t stream) {
    (void)in_sizes; (void)n_in; (void)out_size; (void)ws_size;
    const float* x  = (const float*)d_in[0];
    const float* wq = (const float*)d_in[1];
    const float* bq = (const float*)d_in[2];
    const float* wk = (const float*)d_in[3];
    const float* bk = (const float*)d_in[4];
    const float* wv = (const float*)d_in[5];
    const float* bv = (const float*)d_in[6];
    const float* wo = (const float*)d_in[7];
    const float* bo = (const float*)d_in[8];
    float* out = (float*)d_out;

    unsigned short* ws = (unsigned short*)d_ws;
    const size_t NX = (size_t)MROWS * D_MODEL;
    const size_t NW = (size_t)D_MODEL * D_MODEL;
    unsigned short* xb  = ws;
    unsigned short* wqb = xb + NX;
    unsigned short* wkb = wqb + NW;
    unsigned short* wvb = wkb + NW;
    unsigned short* wob = wvb + NW;
    unsigned short* Qb  = wob + NW;
    unsigned short* Kb  = Qb + NX;
    unsigned short* VTb = Kb + NX;   // V^T: [D_MODEL][MROWS]
    unsigned short* Ab  = VTb + NX;

    const unsigned cvt_blocks = (unsigned)((NX + 4 * NW) / 1024);  // 24576
    cvt_all<<<cvt_blocks, 256, 0, stream>>>(x, wq, wk, wv, wo, xb);

    gemm8qk<<<256, 512, 0, stream>>>(xb, wqb, wkb, bq, bk, Qb, Kb);
    gemmV<<<256, 512, 0, stream>>>(wvb, xb, bv, VTb);

    flash_attn3<<<512, 256, 0, stream>>>(Qb, Kb, VTb, Ab);

    gemmT1<<<256, 512, 0, stream>>>(Ab, wob, bo, out);
}